// Round 8
// baseline (280.374 us; speedup 1.0000x reference)
//
#include <hip/hip_runtime.h>
#include <hip/hip_bf16.h>

// Established facts (R1..R7 on HW):
//  - Harness I/O is FP32; ~170us of dur_us is fixed harness overhead (R1/R6/R7 accounting).
//  - MFMA 16x16x32_bf16 layouts verified in-harness (R6/R7):
//      A[m=lane&15][k=(lane>>4)*8+j], B[n=lane&15][k=(lane>>4)*8+j],
//      C/D col=lane&15, row=(lane>>4)*4+reg.
//  - R7: prep_node 98us = stage+L1 core (latency/L2-traffic bound; MfmaUtil 7%).
//    This round: 2 graphs/block (B-frag reuse when branches match), hoisted stage
//    loads, direct-from-acc L2 epilogue (one wave per graph x m-tile, full K).

#define G_   4096
#define NPG_ 32
#define NN_  (G_*NPG_)     // 131072
#define D_   256
#define SH_  256
#define HDG_ 50
#define HDN_ 3

// output layout (fp32 elements): g_head | n_head | g_var | n_var
#define OFF_GH 0
#define OFF_NH (G_*HDG_)             // 204800
#define OFF_GV (OFF_NH + NN_*HDN_)   // 598016
#define OFF_NV (OFF_GV + G_*HDG_)    // 802816

typedef short v8s __attribute__((ext_vector_type(8)));   // 8 bf16 = 16 B (MFMA A/B frag)
typedef short v4s __attribute__((ext_vector_type(4)));
typedef float v4f __attribute__((ext_vector_type(4)));   // MFMA C/D frag

__device__ __forceinline__ float bfu2f(unsigned short u) {
    return __uint_as_float(((unsigned int)u) << 16);
}
__device__ __forceinline__ unsigned short f2bfu(float v) {
    __hip_bfloat16 b = __float2bfloat16(v);
    return *reinterpret_cast<unsigned short*>(&b);
}

#define MFMA16(a, b, c) __builtin_amdgcn_mfma_f32_16x16x32_bf16((a), (b), (c), 0, 0, 0)

// ---- weight packing (fp32 -> bf16, B-fragment layouts) — R7-verbatim ----
__global__ __launch_bounds__(256) void wpack(const float* __restrict__ Wn1,
                                             const float* __restrict__ Wgs,
                                             const float* __restrict__ Wgh,
                                             const float* __restrict__ Wn2,
                                             unsigned short* __restrict__ out) {
    const int idx = blockIdx.x * 256 + threadIdx.x;   // 0 .. 335871
    float v;
    if (idx < 131072) {
        const int b = idx >> 16, rem = idx & 65535, s = rem >> 8, d = rem & 255;
        v = Wn1[b * 65536 + d * 256 + s];
    } else if (idx < 262144) {
        const int i2 = idx - 131072;
        const int np = i2 >> 8, d = i2 & 255;
        v = Wgs[(np >> 8) * 65536 + d * 256 + (np & 255)];
    } else if (idx < 327680) {
        const int i3 = idx - 262144;
        const int npp = i3 >> 8, k = i3 & 255;
        const int b = npp >> 7, c = npp & 127;
        v = (c < 100) ? Wgh[b * 25600 + k * 100 + c] : 0.f;
    } else {
        const int i4 = idx - 327680;
        const int b = i4 >> 12, rem = i4 & 4095, n = rem >> 8, k = rem & 255;
        v = (n < 6) ? Wn2[b * 1536 + k * 6 + n] : 0.f;
    }
    out[idx] = f2bfu(v);
}

// ---- node kernel: 2 graphs (64 nodes)/block, 2048 blocks.
// stage(hoisted) + mean + L1 MFMA (B reuse when branches match) + L2 direct. ----
#define TSZ (NPG_ * 264)   // u16 elems per graph tile (16896 B)
__global__ __launch_bounds__(256, 3) void prep_node2(const float* __restrict__ x,
                                                     const int* __restrict__ dsname,
                                                     const unsigned short* __restrict__ Wn1T,
                                                     const float* __restrict__ bn1,
                                                     const unsigned short* __restrict__ Wn2b,
                                                     const float* __restrict__ bn2,
                                                     unsigned short* __restrict__ xg,
                                                     float* __restrict__ out) {
    __shared__ __align__(16) unsigned short xs[2 * TSZ];   // 33.8 KB: 2 bf16 x-tiles, then h
    __shared__ __align__(16) float red[2 * 4 * 256];       // 8 KB mean partials
    __shared__ int bls[2];
    const int g0 = blockIdx.x * 2, t = threadIdx.x;
    const int wave = t >> 6, lane = t & 63;
    const int l15 = lane & 15, quad = lane >> 4;
    if (t < 2) bls[t] = dsname[g0 + t];

    // ---- stage both graphs: 8 hoisted float4 loads each, fp32 mean partials ----
    const int colb = (t & 63) * 4;
    const int rb = t >> 6;
    #pragma unroll
    for (int j = 0; j < 2; j++) {
        const float* xb = x + (size_t)(g0 + j) * 8192;
        float4 v[8];
        #pragma unroll
        for (int k = 0; k < 8; k++)
            v[k] = *(const float4*)(xb + (rb + k * 4) * 256 + colb);
        float s0 = 0.f, s1 = 0.f, s2 = 0.f, s3 = 0.f;
        #pragma unroll
        for (int k = 0; k < 8; k++) {
            s0 += v[k].x; s1 += v[k].y; s2 += v[k].z; s3 += v[k].w;
            v4s bv; bv[0] = (short)f2bfu(v[k].x); bv[1] = (short)f2bfu(v[k].y);
                    bv[2] = (short)f2bfu(v[k].z); bv[3] = (short)f2bfu(v[k].w);
            *(v4s*)(&xs[j * TSZ + (rb + k * 4) * 264 + colb]) = bv;
        }
        *(float4*)(&red[(j * 4 + rb) * 256 + colb]) = make_float4(s0, s1, s2, s3);
    }
    __syncthreads();

    // mean -> xg (both graphs)
    xg[(size_t)g0 * 256 + t] =
        f2bfu((red[t] + red[256 + t] + red[512 + t] + red[768 + t]) * (1.0f / NPG_));
    xg[(size_t)(g0 + 1) * 256 + t] =
        f2bfu((red[1024 + t] + red[1280 + t] + red[1536 + t] + red[1792 + t]) * (1.0f / NPG_));

    // ---- L1 MFMA: M=64 (2 graphs x 2 mtiles), per wave N=64 (4 ntiles), K=256 ----
    const int b0 = bls[0], b1 = bls[1];
    v4f acc[4][4];   // [mt: j*2+mtl][nt]
    #pragma unroll
    for (int mt = 0; mt < 4; mt++)
        #pragma unroll
        for (int nt = 0; nt < 4; nt++) acc[mt][nt] = (v4f){0.f, 0.f, 0.f, 0.f};

    const int aoff = l15 * 264 + quad * 8;   // + j*TSZ + mtl*16*264 + ko
    const unsigned short* Bb0 = Wn1T + b0 * 65536 + (wave * 64 + l15) * 256 + quad * 8;

    if (b0 == b1) {
        // shared-B fast path: 4 B loads serve 16 MFMAs per kt
        #pragma unroll
        for (int kt = 0; kt < 8; kt++) {
            const int ko = kt * 32;
            v8s bf0 = *(const v8s*)(Bb0 + ko);
            v8s bf1 = *(const v8s*)(Bb0 + 4096 + ko);
            v8s bf2 = *(const v8s*)(Bb0 + 8192 + ko);
            v8s bf3 = *(const v8s*)(Bb0 + 12288 + ko);
            #pragma unroll
            for (int mt = 0; mt < 4; mt++) {
                v8s a = *(const v8s*)(&xs[(mt >> 1) * TSZ + (mt & 1) * 16 * 264 + aoff + ko]);
                acc[mt][0] = MFMA16(a, bf0, acc[mt][0]);
                acc[mt][1] = MFMA16(a, bf1, acc[mt][1]);
                acc[mt][2] = MFMA16(a, bf2, acc[mt][2]);
                acc[mt][3] = MFMA16(a, bf3, acc[mt][3]);
            }
        }
    } else {
        const unsigned short* Bb1 = Wn1T + b1 * 65536 + (wave * 64 + l15) * 256 + quad * 8;
        #pragma unroll
        for (int kt = 0; kt < 8; kt++) {
            const int ko = kt * 32;
            v8s bf0 = *(const v8s*)(Bb0 + ko);
            v8s bf1 = *(const v8s*)(Bb0 + 4096 + ko);
            v8s bf2 = *(const v8s*)(Bb0 + 8192 + ko);
            v8s bf3 = *(const v8s*)(Bb0 + 12288 + ko);
            #pragma unroll
            for (int mt = 0; mt < 2; mt++) {
                v8s a = *(const v8s*)(&xs[(mt & 1) * 16 * 264 + aoff + ko]);
                acc[mt][0] = MFMA16(a, bf0, acc[mt][0]);
                acc[mt][1] = MFMA16(a, bf1, acc[mt][1]);
                acc[mt][2] = MFMA16(a, bf2, acc[mt][2]);
                acc[mt][3] = MFMA16(a, bf3, acc[mt][3]);
            }
        }
        #pragma unroll
        for (int kt = 0; kt < 8; kt++) {
            const int ko = kt * 32;
            v8s bf0 = *(const v8s*)(Bb1 + ko);
            v8s bf1 = *(const v8s*)(Bb1 + 4096 + ko);
            v8s bf2 = *(const v8s*)(Bb1 + 8192 + ko);
            v8s bf3 = *(const v8s*)(Bb1 + 12288 + ko);
            #pragma unroll
            for (int mt = 2; mt < 4; mt++) {
                v8s a = *(const v8s*)(&xs[TSZ + (mt & 1) * 16 * 264 + aoff + ko]);
                acc[mt][0] = MFMA16(a, bf0, acc[mt][0]);
                acc[mt][1] = MFMA16(a, bf1, acc[mt][1]);
                acc[mt][2] = MFMA16(a, bf2, acc[mt][2]);
                acc[mt][3] = MFMA16(a, bf3, acc[mt][3]);
            }
        }
    }
    __syncthreads();   // all A reads done; reuse xs for h

    // bias + ReLU -> h (bf16) into xs (per graph tile)
    #pragma unroll
    for (int mt = 0; mt < 4; mt++) {
        const int j = mt >> 1;
        const int bj = j ? b1 : b0;
        #pragma unroll
        for (int nt = 0; nt < 4; nt++) {
            const int col = wave * 64 + nt * 16 + l15;
            const float bias = bn1[bj * 256 + col];
            #pragma unroll
            for (int r = 0; r < 4; r++) {
                const int row = (mt & 1) * 16 + quad * 4 + r;
                const float v = acc[mt][nt][r] + bias;
                xs[j * TSZ + row * 264 + col] = f2bfu(v > 0.f ? v : 0.f);
            }
        }
    }
    __syncthreads();

    // ---- L2 MFMA: wave = (j, mtl); M=16, N=16 (6 valid), full K=256; direct store ----
    {
        const int j = wave >> 1, mtl = wave & 1;
        const int bj = j ? b1 : b0;
        v4f a2 = (v4f){0.f, 0.f, 0.f, 0.f};
        const unsigned short* Bp = Wn2b + bj * 4096 + l15 * 256 + quad * 8;
        #pragma unroll
        for (int kt = 0; kt < 8; kt++) {
            const int ko = kt * 32;
            v8s av = *(const v8s*)(&xs[j * TSZ + (mtl * 16 + l15) * 264 + ko + quad * 8]);
            v8s bv = *(const v8s*)(Bp + ko);
            a2 = MFMA16(av, bv, a2);
        }
        if (l15 < 6) {
            const float bias = bn2[bj * 6 + l15];
            #pragma unroll
            for (int r = 0; r < 4; r++) {
                const int row = mtl * 16 + quad * 4 + r;
                const int n = (g0 + j) * NPG_ + row;
                const float o = a2[r] + bias;
                if (l15 < HDN_) out[OFF_NH + n * HDN_ + l15] = o;
                else            out[OFF_NV + n * HDN_ + (l15 - HDN_)] = o * o;
            }
        }
    }
}

// ---- graph MLP, all-MFMA — R7-verbatim (proven) ----
__global__ __launch_bounds__(256) void graph_mfma2(const unsigned short* __restrict__ xg,
                                                   const int* __restrict__ dsname,
                                                   const unsigned short* __restrict__ WgsT,
                                                   const float* __restrict__ bgs,
                                                   const unsigned short* __restrict__ WghP,
                                                   const float* __restrict__ bgh,
                                                   float* __restrict__ out) {
    __shared__ __align__(16) unsigned short xs[32 * 264];
    __shared__ int bls[32];
    const int gbase = blockIdx.x * 32;
    const int t = threadIdx.x;
    const int wave = t >> 6, lane = t & 63;
    const int l15 = lane & 15, quad = lane >> 4;
    if (t < 32) bls[t] = dsname[gbase + t];

    #pragma unroll
    for (int k = 0; k < 4; k++) {
        const int flat = k * 2048 + t * 8;
        *(v8s*)(&xs[(flat >> 8) * 264 + (flat & 255)]) =
            *(const v8s*)(xg + (size_t)gbase * 256 + flat);
    }
    __syncthreads();

    v4f acc[2][8];
    #pragma unroll
    for (int mt = 0; mt < 2; mt++)
        #pragma unroll
        for (int nt = 0; nt < 8; nt++) acc[mt][nt] = (v4f){0.f, 0.f, 0.f, 0.f};

    const unsigned short* Ab = &xs[l15 * 264 + quad * 8];
    const unsigned short* Bb = WgsT + (wave * 128 + l15) * 256 + quad * 8;

    #pragma unroll
    for (int kt = 0; kt < 8; kt++) {
        const int ko = kt * 32;
        v8s a0 = *(const v8s*)(Ab + ko);
        v8s a1 = *(const v8s*)(Ab + 16 * 264 + ko);
        #pragma unroll
        for (int nt = 0; nt < 8; nt++) {
            v8s bv = *(const v8s*)(Bb + nt * 16 * 256 + ko);
            acc[0][nt] = MFMA16(a0, bv, acc[0][nt]);
            acc[1][nt] = MFMA16(a1, bv, acc[1][nt]);
        }
    }
    __syncthreads();

    {
        const int bw = wave >> 1;
        #pragma unroll
        for (int nt = 0; nt < 8; nt++) {
            const int sp = wave * 128 + nt * 16 + l15;
            const int s_local = sp & 255;
            const float bias = bgs[sp];
            #pragma unroll
            for (int mt = 0; mt < 2; mt++)
                #pragma unroll
                for (int r = 0; r < 4; r++) {
                    const int row = mt * 16 + quad * 4 + r;
                    if (bls[row] == bw) {
                        const float v = acc[mt][nt][r] + bias;
                        xs[row * 264 + s_local] = f2bfu(v > 0.f ? v : 0.f);
                    }
                }
        }
    }
    __syncthreads();

    v4f acc2[2][4];
    #pragma unroll
    for (int mt = 0; mt < 2; mt++)
        #pragma unroll
        for (int nt = 0; nt < 4; nt++) acc2[mt][nt] = (v4f){0.f, 0.f, 0.f, 0.f};

    const unsigned short* B2 = WghP + ((wave * 4) * 16 + l15) * 256 + quad * 8;
    #pragma unroll
    for (int kt = 0; kt < 8; kt++) {
        const int ko = kt * 32;
        v8s a0 = *(const v8s*)(&xs[l15 * 264 + ko + quad * 8]);
        v8s a1 = *(const v8s*)(&xs[(16 + l15) * 264 + ko + quad * 8]);
        #pragma unroll
        for (int nt = 0; nt < 4; nt++) {
            v8s bv = *(const v8s*)(B2 + nt * 16 * 256 + ko);
            acc2[0][nt] = MFMA16(a0, bv, acc2[0][nt]);
            acc2[1][nt] = MFMA16(a1, bv, acc2[1][nt]);
        }
    }

    #pragma unroll
    for (int nt = 0; nt < 4; nt++) {
        const int npp  = (wave * 4 + nt) * 16 + l15;
        const int bo   = npp >> 7, c = npp & 127;
        if (c < 2 * HDG_) {
            const float bias = bgh[bo * 2 * HDG_ + c];
            #pragma unroll
            for (int mt = 0; mt < 2; mt++)
                #pragma unroll
                for (int r = 0; r < 4; r++) {
                    const int row = mt * 16 + quad * 4 + r;
                    if (bls[row] == bo) {
                        const float o = acc2[mt][nt][r] + bias;
                        const int g = gbase + row;
                        if (c < HDG_) out[OFF_GH + g * HDG_ + c] = o;
                        else          out[OFF_GV + g * HDG_ + (c - HDG_)] = o * o;
                    }
                }
        }
    }
}

extern "C" void kernel_launch(void* const* d_in, const int* in_sizes, int n_in,
                              void* d_out, int out_size, void* d_ws, size_t ws_size,
                              hipStream_t stream) {
    const float* x      = (const float*)d_in[0];
    const int*   dsname = (const int*)d_in[1];
    // d_in[2] = batch: arange(N)//32 by construction; structure used directly.
    const float* Wgs = (const float*)d_in[3];
    const float* bgs = (const float*)d_in[4];
    const float* Wgh = (const float*)d_in[5];
    const float* bgh = (const float*)d_in[6];
    const float* Wn1 = (const float*)d_in[7];
    const float* bn1 = (const float*)d_in[8];
    const float* Wn2 = (const float*)d_in[9];
    const float* bn2 = (const float*)d_in[10];
    float* out = (float*)d_out;

    unsigned short* wsbuf = (unsigned short*)d_ws;
    unsigned short* Wn1T  = wsbuf;              // @0       (131072 elems)
    unsigned short* WgsT  = wsbuf + 131072;     // @262144B (131072)
    unsigned short* WghP  = wsbuf + 262144;     // @524288B (65536)
    unsigned short* Wn2b  = wsbuf + 327680;     // @655360B (8192)
    unsigned short* xg    = wsbuf + 335872;     // @671744B (1048576 elems, 2MB)

    wpack      <<<1312,    256, 0, stream>>>(Wn1, Wgs, Wgh, Wn2, wsbuf);
    prep_node2 <<<G_ / 2,  256, 0, stream>>>(x, dsname, Wn1T, bn1, Wn2b, bn2, xg, out);
    graph_mfma2<<<G_ / 32, 256, 0, stream>>>(xg, dsname, WgsT, bgs, WghP, bgh, out);
}

// Round 9
// 245.053 us; speedup vs baseline: 1.1441x; 1.1441x over previous
//
#include <hip/hip_runtime.h>
#include <hip/hip_bf16.h>

// Established facts (R1..R8 on HW):
//  - Harness I/O is FP32; ~170us of dur_us is fixed harness overhead.
//  - MFMA 16x16x32_bf16 layouts verified in-harness (R6/R7/R8):
//      A[m=lane&15][k=(lane>>4)*8+j], B[n=lane&15][k=(lane>>4)*8+j],
//      C/D col=lane&15, row=(lane>>4)*4+reg.
//  - R7=R8=98us invariant to B-traffic/occupancy/hoisting -> short-lived-block
//    latency chain (cold x HBM latency + in-loop L2 B loads + barrier drains).
//    This round: persistent branch-partitioned blocks, B in REGISTERS loaded
//    once per block, software-pipelined x prefetch across the graph loop.

#define G_   4096
#define NPG_ 32
#define NN_  (G_*NPG_)     // 131072
#define D_   256
#define SH_  256
#define HDG_ 50
#define HDN_ 3

// output layout (fp32 elements): g_head | n_head | g_var | n_var
#define OFF_GH 0
#define OFF_NH (G_*HDG_)             // 204800
#define OFF_GV (OFF_NH + NN_*HDN_)   // 598016
#define OFF_NV (OFF_GV + G_*HDG_)    // 802816

typedef short v8s __attribute__((ext_vector_type(8)));   // 8 bf16 = 16 B (MFMA A/B frag)
typedef short v4s __attribute__((ext_vector_type(4)));
typedef float v4f __attribute__((ext_vector_type(4)));   // MFMA C/D frag

__device__ __forceinline__ float bfu2f(unsigned short u) {
    return __uint_as_float(((unsigned int)u) << 16);
}
__device__ __forceinline__ unsigned short f2bfu(float v) {
    __hip_bfloat16 b = __float2bfloat16(v);
    return *reinterpret_cast<unsigned short*>(&b);
}

#define MFMA16(a, b, c) __builtin_amdgcn_mfma_f32_16x16x32_bf16((a), (b), (c), 0, 0, 0)

// ---- weight packing (fp32 -> bf16, B-fragment layouts) — R7-verbatim ----
__global__ __launch_bounds__(256) void wpack(const float* __restrict__ Wn1,
                                             const float* __restrict__ Wgs,
                                             const float* __restrict__ Wgh,
                                             const float* __restrict__ Wn2,
                                             unsigned short* __restrict__ out) {
    const int idx = blockIdx.x * 256 + threadIdx.x;   // 0 .. 335871
    float v;
    if (idx < 131072) {
        const int b = idx >> 16, rem = idx & 65535, s = rem >> 8, d = rem & 255;
        v = Wn1[b * 65536 + d * 256 + s];
    } else if (idx < 262144) {
        const int i2 = idx - 131072;
        const int np = i2 >> 8, d = i2 & 255;
        v = Wgs[(np >> 8) * 65536 + d * 256 + (np & 255)];
    } else if (idx < 327680) {
        const int i3 = idx - 262144;
        const int npp = i3 >> 8, k = i3 & 255;
        const int b = npp >> 7, c = npp & 127;
        v = (c < 100) ? Wgh[b * 25600 + k * 100 + c] : 0.f;
    } else {
        const int i4 = idx - 327680;
        const int b = i4 >> 12, rem = i4 & 4095, n = rem >> 8, k = rem & 255;
        v = (n < 6) ? Wn2[b * 1536 + k * 6 + n] : 0.f;
    }
    out[idx] = f2bfu(v);
}

// ---- per-branch graph lists (order irrelevant) ----
__global__ void build_glist(const int* __restrict__ dsname,
                            int* __restrict__ glist,    // [2][4096]
                            int* __restrict__ gcnt) {   // [2]
    __shared__ int cnt[2];
    const int t = threadIdx.x;   // 256
    if (t < 2) cnt[t] = 0;
    __syncthreads();
    for (int i = 0; i < 16; i++) {
        const int g = i * 256 + t;
        const int b = dsname[g];
        const int slot = atomicAdd(&cnt[b], 1);
        glist[b * G_ + slot] = g;
    }
    __syncthreads();
    if (t < 2) gcnt[t] = cnt[t];
}

// ---- persistent node kernel: 256 blocks x 512 threads (8 waves).
// block branch = blockIdx&1; handles ~16 graphs via grid-stride over glist.
// Wave's L1 B-fragments (2 n-tiles x 8 kt) live in registers for the whole block. ----
__global__ __launch_bounds__(512) void node_pers(const float* __restrict__ x,
                                                 const int* __restrict__ glist,
                                                 const int* __restrict__ gcnt,
                                                 const unsigned short* __restrict__ Wn1T,
                                                 const float* __restrict__ bn1,
                                                 const unsigned short* __restrict__ Wn2b,
                                                 const float* __restrict__ bn2,
                                                 unsigned short* __restrict__ xg,
                                                 float* __restrict__ out) {
    __shared__ __align__(16) unsigned short xs[NPG_ * 264];   // 16.9 KB: bf16 x-tile, then h
    __shared__ __align__(16) float red[8 * 256];              // 8 KB: mean partials / L2 partials
    const int t = threadIdx.x;
    const int wave = t >> 6, lane = t & 63;
    const int l15 = lane & 15, quad = lane >> 4;
    const int br = blockIdx.x & 1;
    const int bslot = blockIdx.x >> 1;        // 0..127
    const int cnt = gcnt[br];

    // wave's hidden columns: base_n + nt*16 + l15 (nt<2); union over 8 waves = 0..255
    const int base_n = (wave & 1) * 128 + (wave >> 1) * 32;

    // L1 B fragments + bias: loaded ONCE per block
    v8s B1[2][8];
    float bias1[2];
    #pragma unroll
    for (int nt = 0; nt < 2; nt++) {
        const unsigned short* bp = Wn1T + br * 65536 + (base_n + nt * 16 + l15) * 256 + quad * 8;
        #pragma unroll
        for (int kt = 0; kt < 8; kt++) B1[nt][kt] = *(const v8s*)(bp + kt * 32);
        bias1[nt] = bn1[br * 256 + base_n + nt * 16 + l15];
    }

    // L2 B fragments for waves 0..3 (wave = (kh=w>>1, mtl=w&1)): once per block
    v8s B2[4];
    if (wave < 4) {
        const int kh = wave >> 1;
        const unsigned short* bp = Wn2b + br * 4096 + l15 * 256 + kh * 128 + quad * 8;
        #pragma unroll
        for (int j = 0; j < 4; j++) B2[j] = *(const v8s*)(bp + j * 32);
    }
    float bias2 = 0.f; int i2 = 0, c2 = 0;
    if (t < 192) { i2 = t / 6; c2 = t % 6; bias2 = bn2[br * 6 + c2]; }

    const int rb = t >> 6;            // 0..7: rows rb*4..rb*4+3
    const int colb = (t & 63) * 4;    // 16-B coalesced columns

    // prefetch first graph
    int gi = bslot;
    int g = glist[br * G_ + ((gi < cnt) ? gi : (cnt - 1))];
    float4 pv[4];
    #pragma unroll
    for (int k = 0; k < 4; k++)
        pv[k] = *(const float4*)(x + (size_t)g * 8192 + (rb * 4 + k) * 256 + colb);

    for (; gi < cnt; gi += 128) {
        const int gcur = g;
        // convert pv -> xs (bf16) + fp32 mean partials
        float s0 = 0.f, s1 = 0.f, s2 = 0.f, s3 = 0.f;
        #pragma unroll
        for (int k = 0; k < 4; k++) {
            s0 += pv[k].x; s1 += pv[k].y; s2 += pv[k].z; s3 += pv[k].w;
            v4s bv; bv[0] = (short)f2bfu(pv[k].x); bv[1] = (short)f2bfu(pv[k].y);
                    bv[2] = (short)f2bfu(pv[k].z); bv[3] = (short)f2bfu(pv[k].w);
            *(v4s*)(&xs[(rb * 4 + k) * 264 + colb]) = bv;
        }
        *(float4*)(&red[rb * 256 + colb]) = make_float4(s0, s1, s2, s3);

        // prefetch NEXT graph (latency hidden under MFMA phase)
        {
            const int gi2 = gi + 128;
            const int gn = glist[br * G_ + ((gi2 < cnt) ? gi2 : (cnt - 1))];
            #pragma unroll
            for (int k = 0; k < 4; k++)
                pv[k] = *(const float4*)(x + (size_t)gn * 8192 + (rb * 4 + k) * 256 + colb);
            g = gn;
        }
        __syncthreads();   // A: xs + mean partials visible

        // mean -> xg
        if (t < 256) {
            float m = 0.f;
            #pragma unroll
            for (int r = 0; r < 8; r++) m += red[r * 256 + t];
            xg[(size_t)gcur * 256 + t] = f2bfu(m * (1.0f / NPG_));
        }

        // L1 MFMA: M=32, wave's N=32 (2 n-tiles), K=256; B from registers
        v4f acc[2][2];
        #pragma unroll
        for (int mt = 0; mt < 2; mt++)
            #pragma unroll
            for (int nt = 0; nt < 2; nt++) acc[mt][nt] = (v4f){0.f, 0.f, 0.f, 0.f};
        #pragma unroll
        for (int kt = 0; kt < 8; kt++) {
            const int ko = kt * 32;
            v8s a0 = *(const v8s*)(&xs[l15 * 264 + quad * 8 + ko]);
            v8s a1 = *(const v8s*)(&xs[(16 + l15) * 264 + quad * 8 + ko]);
            #pragma unroll
            for (int nt = 0; nt < 2; nt++) {
                acc[0][nt] = MFMA16(a0, B1[nt][kt], acc[0][nt]);
                acc[1][nt] = MFMA16(a1, B1[nt][kt], acc[1][nt]);
            }
        }
        __syncthreads();   // B: all A reads done; xs becomes h

        // bias + ReLU -> h (bf16) into xs
        #pragma unroll
        for (int nt = 0; nt < 2; nt++) {
            const int col = base_n + nt * 16 + l15;
            #pragma unroll
            for (int mt = 0; mt < 2; mt++)
                #pragma unroll
                for (int r = 0; r < 4; r++) {
                    const int row = mt * 16 + quad * 4 + r;
                    const float v = acc[mt][nt][r] + bias1[nt];
                    xs[row * 264 + col] = f2bfu(v > 0.f ? v : 0.f);
                }
        }
        __syncthreads();   // C: h complete

        // L2 MFMA: waves 0..3, M=16 (mtl), N=16 (6 valid), K=128 (kh); partials -> red
        if (wave < 4) {
            const int mtl = wave & 1, kh = wave >> 1;
            v4f a2 = (v4f){0.f, 0.f, 0.f, 0.f};
            #pragma unroll
            for (int j = 0; j < 4; j++) {
                const int ko = kh * 128 + j * 32;
                v8s av = *(const v8s*)(&xs[(mtl * 16 + l15) * 264 + ko + quad * 8]);
                a2 = MFMA16(av, B2[j], a2);
            }
            #pragma unroll
            for (int r = 0; r < 4; r++)
                red[kh * 512 + (mtl * 16 + quad * 4 + r) * 16 + l15] = a2[r];
        }
        __syncthreads();   // D: partials visible

        if (t < 192) {
            const float o = red[i2 * 16 + c2] + red[512 + i2 * 16 + c2] + bias2;
            const int n = gcur * NPG_ + i2;
            if (c2 < HDN_) out[OFF_NH + n * HDN_ + c2] = o;
            else           out[OFF_NV + n * HDN_ + (c2 - HDN_)] = o * o;
        }
        __syncthreads();   // E: red/xs free for next graph
    }
}

// ---- graph MLP, all-MFMA — R7-verbatim (proven) ----
__global__ __launch_bounds__(256) void graph_mfma2(const unsigned short* __restrict__ xg,
                                                   const int* __restrict__ dsname,
                                                   const unsigned short* __restrict__ WgsT,
                                                   const float* __restrict__ bgs,
                                                   const unsigned short* __restrict__ WghP,
                                                   const float* __restrict__ bgh,
                                                   float* __restrict__ out) {
    __shared__ __align__(16) unsigned short xs[32 * 264];
    __shared__ int bls[32];
    const int gbase = blockIdx.x * 32;
    const int t = threadIdx.x;
    const int wave = t >> 6, lane = t & 63;
    const int l15 = lane & 15, quad = lane >> 4;
    if (t < 32) bls[t] = dsname[gbase + t];

    #pragma unroll
    for (int k = 0; k < 4; k++) {
        const int flat = k * 2048 + t * 8;
        *(v8s*)(&xs[(flat >> 8) * 264 + (flat & 255)]) =
            *(const v8s*)(xg + (size_t)gbase * 256 + flat);
    }
    __syncthreads();

    v4f acc[2][8];
    #pragma unroll
    for (int mt = 0; mt < 2; mt++)
        #pragma unroll
        for (int nt = 0; nt < 8; nt++) acc[mt][nt] = (v4f){0.f, 0.f, 0.f, 0.f};

    const unsigned short* Ab = &xs[l15 * 264 + quad * 8];
    const unsigned short* Bb = WgsT + (wave * 128 + l15) * 256 + quad * 8;

    #pragma unroll
    for (int kt = 0; kt < 8; kt++) {
        const int ko = kt * 32;
        v8s a0 = *(const v8s*)(Ab + ko);
        v8s a1 = *(const v8s*)(Ab + 16 * 264 + ko);
        #pragma unroll
        for (int nt = 0; nt < 8; nt++) {
            v8s bv = *(const v8s*)(Bb + nt * 16 * 256 + ko);
            acc[0][nt] = MFMA16(a0, bv, acc[0][nt]);
            acc[1][nt] = MFMA16(a1, bv, acc[1][nt]);
        }
    }
    __syncthreads();

    {
        const int bw = wave >> 1;
        #pragma unroll
        for (int nt = 0; nt < 8; nt++) {
            const int sp = wave * 128 + nt * 16 + l15;
            const int s_local = sp & 255;
            const float bias = bgs[sp];
            #pragma unroll
            for (int mt = 0; mt < 2; mt++)
                #pragma unroll
                for (int r = 0; r < 4; r++) {
                    const int row = mt * 16 + quad * 4 + r;
                    if (bls[row] == bw) {
                        const float v = acc[mt][nt][r] + bias;
                        xs[row * 264 + s_local] = f2bfu(v > 0.f ? v : 0.f);
                    }
                }
        }
    }
    __syncthreads();

    v4f acc2[2][4];
    #pragma unroll
    for (int mt = 0; mt < 2; mt++)
        #pragma unroll
        for (int nt = 0; nt < 4; nt++) acc2[mt][nt] = (v4f){0.f, 0.f, 0.f, 0.f};

    const unsigned short* B2 = WghP + ((wave * 4) * 16 + l15) * 256 + quad * 8;
    #pragma unroll
    for (int kt = 0; kt < 8; kt++) {
        const int ko = kt * 32;
        v8s a0 = *(const v8s*)(&xs[l15 * 264 + ko + quad * 8]);
        v8s a1 = *(const v8s*)(&xs[(16 + l15) * 264 + ko + quad * 8]);
        #pragma unroll
        for (int nt = 0; nt < 4; nt++) {
            v8s bv = *(const v8s*)(B2 + nt * 16 * 256 + ko);
            acc2[0][nt] = MFMA16(a0, bv, acc2[0][nt]);
            acc2[1][nt] = MFMA16(a1, bv, acc2[1][nt]);
        }
    }

    #pragma unroll
    for (int nt = 0; nt < 4; nt++) {
        const int npp  = (wave * 4 + nt) * 16 + l15;
        const int bo   = npp >> 7, c = npp & 127;
        if (c < 2 * HDG_) {
            const float bias = bgh[bo * 2 * HDG_ + c];
            #pragma unroll
            for (int mt = 0; mt < 2; mt++)
                #pragma unroll
                for (int r = 0; r < 4; r++) {
                    const int row = mt * 16 + quad * 4 + r;
                    if (bls[row] == bo) {
                        const float o = acc2[mt][nt][r] + bias;
                        const int g = gbase + row;
                        if (c < HDG_) out[OFF_GH + g * HDG_ + c] = o;
                        else          out[OFF_GV + g * HDG_ + (c - HDG_)] = o * o;
                    }
                }
        }
    }
}

extern "C" void kernel_launch(void* const* d_in, const int* in_sizes, int n_in,
                              void* d_out, int out_size, void* d_ws, size_t ws_size,
                              hipStream_t stream) {
    const float* x      = (const float*)d_in[0];
    const int*   dsname = (const int*)d_in[1];
    // d_in[2] = batch: arange(N)//32 by construction; structure used directly.
    const float* Wgs = (const float*)d_in[3];
    const float* bgs = (const float*)d_in[4];
    const float* Wgh = (const float*)d_in[5];
    const float* bgh = (const float*)d_in[6];
    const float* Wn1 = (const float*)d_in[7];
    const float* bn1 = (const float*)d_in[8];
    const float* Wn2 = (const float*)d_in[9];
    const float* bn2 = (const float*)d_in[10];
    float* out = (float*)d_out;

    unsigned short* wsbuf = (unsigned short*)d_ws;
    unsigned short* Wn1T  = wsbuf;              // @0        (131072 u16)
    unsigned short* WgsT  = wsbuf + 131072;     // @262144B  (131072)
    unsigned short* WghP  = wsbuf + 262144;     // @524288B  (65536)
    unsigned short* Wn2b  = wsbuf + 327680;     // @655360B  (8192)
    unsigned short* xg    = wsbuf + 335872;     // @671744B  (1048576 u16, 2MB)
    int* glist = (int*)((char*)d_ws + 2768896); // 2*4096 ints
    int* gcnt  = (int*)((char*)d_ws + 2801664); // 2 ints

    wpack      <<<1312,    256, 0, stream>>>(Wn1, Wgs, Wgh, Wn2, wsbuf);
    build_glist<<<1,       256, 0, stream>>>(dsname, glist, gcnt);
    node_pers  <<<256,     512, 0, stream>>>(x, glist, gcnt, Wn1T, bn1, Wn2b, bn2, xg, out);
    graph_mfma2<<<G_ / 32, 256, 0, stream>>>(xg, dsname, WgsT, bgs, WghP, bgh, out);
}